// Round 22
// baseline (50.195 us; speedup 1.0000x reference)
//
#include <hip/hip_runtime.h>
#include <math.h>

// B=4, X=128, T=256, HIDDEN=128, EMB=128, DH=32, LATENT=32, K=1024
// Outputs concat: u (131072), zt (1048576), px (524288)
//
// R22: u via M-algebra (R12/R13-validated):
//   u[b,t,x] = K0 + mz*mp*( ft.M.fx + ft.a + bvec.fx + c0 )
//   M[jt][jx] = sum_k zt_Wo[jt,k] wc_k px_Wo[jx,k]  (stored transposed Mt[jx][jt])
// prep (133 blocks): 0-3 chains->gx/gt; 4 wc/K0/a/bvec/c0; 5-132 M tiles.
// main (416 blocks): 0-383 MFMA feat (R21, g from ws); 384-415 u via two
//   chained 32x128x128 MFMA GEMMs (fragment formulas validated R20/R21).

typedef __attribute__((ext_vector_type(8))) short short8v;   // 8 bf16
typedef __attribute__((ext_vector_type(4))) float f32x4;

#define WS_WC  0
#define WS_K0  32
#define WS_C0  33
#define WS_A   64
#define WS_BV  192
#define WS_GX  512
#define WS_GT  1024
#define WS_M   2048

struct P {
    const float *x, *t, *param;
    const float *p2e_W1, *p2e_b1, *p2e_W2, *p2e_b2;
    const float *e2ex_W, *e2ex_b, *e2et_W, *e2et_b;
    const float *px_Wx, *px_bx, *px_We, *px_be, *px_Wo, *px_bo, *px_mult;
    const float *zt_Wx, *zt_bx, *zt_We, *zt_be, *zt_Wo, *zt_bo, *zt_mult;
    const float *h0, *blk_W1, *blk_b1, *blk_Wc, *blk_bc, *blk_W2, *blk_b2;
    const float *d_W, *d_b;
    float *out_u, *out_zt, *out_px, *ws;
};

__device__ __forceinline__ void fma4(float4& a, float s, const float4& v) {
    a.x += s * v.x; a.y += s * v.y; a.z += s * v.z; a.w += s * v.w;
}

__device__ __forceinline__ unsigned short f2bf(float f) {
    unsigned int u = __float_as_uint(f);
    return (unsigned short)((u + 0x7FFFu + ((u >> 16) & 1u)) >> 16);
}

__device__ __forceinline__ float bf2f(unsigned short s) {
    return __uint_as_float(((unsigned int)s) << 16);
}

// out[j] = bias[j] + sum_k vin[k] * W[k*128+j]; 256 threads. (validated)
__device__ __forceinline__ void gemv_stage(
    const float* __restrict__ W, const float* __restrict__ bias,
    const float* vin, float* vout, float* partf, int tid)
{
    const int j4 = tid & 31;
    const int sl = tid >> 5;
    float4 a4 = make_float4(0.f, 0.f, 0.f, 0.f);
    const float* Wp = W + sl * 16 * 128 + j4 * 4;
    #pragma unroll
    for (int k = 0; k < 16; ++k)
        fma4(a4, vin[sl * 16 + k], *(const float4*)&Wp[k * 128]);
    *(float4*)&partf[sl * 128 + j4 * 4] = a4;
    __syncthreads();
    if (tid < 128) {
        float v = bias[tid];
        #pragma unroll
        for (int q = 0; q < 8; ++q) v += partf[q * 128 + tid];
        vout[tid] = v;
    }
    __syncthreads();
}

// sw chain -> wcl[32]; optionally write ws wc + K0. (validated R12/R13)
__device__ __forceinline__ void compute_wc(
    const P& p, float* sA, float* sB, float* partf, float* wcl,
    int tid, bool write_ws)
{
    if (tid < 128) sA[tid] = p.h0[tid];
    __syncthreads();
    gemv_stage(p.blk_W1, p.blk_b1, sA, sB, partf, tid);
    if (tid < 128) {
        float w2 = 0.f;
        const float4* rp = (const float4*)&p.blk_W2[tid * 128];
        #pragma unroll
        for (int m4 = 0; m4 < 32; ++m4) {
            const float4 wv = rp[m4];
            const float4 dv = *(const float4*)&p.d_W[m4 * 4];
            w2 += wv.x * dv.x + wv.y * dv.y + wv.z * dv.z + wv.w * dv.w;
        }
        const float sv = __sinf(sB[tid]) * w2;
        sA[tid] = sv;
        sB[tid] = (p.h0[tid] + p.blk_b2[tid]) * p.d_W[tid] + sv * p.blk_bc[tid];
    }
    __syncthreads();
    {
        const int d  = tid >> 3;
        const int sg = (tid & 7) * 16;
        float acc = 0.f;
        #pragma unroll
        for (int i4 = 0; i4 < 4; ++i4) {
            const float4 wv = *(const float4*)&p.blk_Wc[d * 128 + sg + i4 * 4];
            const float4 sv = *(const float4*)&sA[sg + i4 * 4];
            acc += wv.x * sv.x + wv.y * sv.y + wv.z * sv.z + wv.w * sv.w;
        }
        partf[d * 8 + (tid & 7)] = acc;
    }
    __syncthreads();
    if (tid < 32) {
        float w = 0.f;
        #pragma unroll
        for (int q = 0; q < 8; ++q) w += partf[tid * 8 + q];
        wcl[tid] = w * (1.0f / 32.0f);
        if (write_ws) p.ws[WS_WC + tid] = wcl[tid];
    }
    if (write_ws) {
        if (tid < 64) sB[tid] += sB[tid + 64];
        __syncthreads();
        if (tid == 0) {
            float K = p.d_b[0];
            #pragma unroll
            for (int i = 0; i < 64; ++i) K += sB[i];
            p.ws[WS_K0] = K;
        }
    }
    __syncthreads();
}

__global__ __launch_bounds__(256, 2) void prep_kernel(P p) {
    __shared__ float sA[128], sB[128], sC[128], sD[128];
    __shared__ float partf[1024];
    __shared__ float wcl[32];
    const int tid = threadIdx.x;
    const int bid = blockIdx.x;

    if (bid < 4) {
        const int b = bid;
        if (tid < 128) {
            float a = p.p2e_b1[tid];
            #pragma unroll
            for (int q = 0; q < 16; ++q)
                a += p.param[b * 16 + q] * p.p2e_W1[q * 128 + tid];
            sA[tid] = __sinf(a);
        }
        __syncthreads();
        gemv_stage(p.p2e_W2, p.p2e_b2, sA, sB, partf, tid);   // e
        gemv_stage(p.e2ex_W, p.e2ex_b, sB, sC, partf, tid);   // ex
        gemv_stage(p.e2et_W, p.e2et_b, sB, sD, partf, tid);   // et
        gemv_stage(p.px_We,  p.px_be,  sC, sA, partf, tid);   // gx
        gemv_stage(p.zt_We,  p.zt_be,  sD, sC, partf, tid);   // gt
        if (tid < 128) {
            p.ws[WS_GX + b * 128 + tid] = sA[tid];
            p.ws[WS_GT + b * 128 + tid] = sC[tid];
        }
    } else if (bid == 4) {
        __shared__ float wb[1024], zb[1024];
        compute_wc(p, sA, sB, partf, wcl, tid, true);
        {
            const int k4 = tid * 4;
            const float w = wcl[k4 >> 5];
            float4 bp = *(const float4*)&p.px_bo[k4];
            float4 bz = *(const float4*)&p.zt_bo[k4];
            float4 v1, v2;
            v1.x = w * bp.x; v1.y = w * bp.y; v1.z = w * bp.z; v1.w = w * bp.w;
            v2.x = w * bz.x; v2.y = w * bz.y; v2.z = w * bz.z; v2.w = w * bz.w;
            *(float4*)&wb[k4] = v1;
            *(float4*)&zb[k4] = v2;
            partf[tid] = v2.x * bp.x + v2.y * bp.y + v2.z * bp.z + v2.w * bp.w;
        }
        __syncthreads();
        if (tid < 128) {
            float acc = 0.f;
            const float4* rp = (const float4*)&p.zt_Wo[tid * 1024];
            #pragma unroll 8
            for (int k4 = 0; k4 < 256; ++k4) {
                const float4 wv = rp[k4];
                const float4 cv = *(const float4*)&wb[k4 * 4];
                acc += wv.x * cv.x + wv.y * cv.y + wv.z * cv.z + wv.w * cv.w;
            }
            p.ws[WS_A + tid] = acc;
        } else {
            const int i = tid - 128;
            float acc = 0.f;
            const float4* rp = (const float4*)&p.px_Wo[i * 1024];
            #pragma unroll 8
            for (int k4 = 0; k4 < 256; ++k4) {
                const float4 wv = rp[k4];
                const float4 cv = *(const float4*)&zb[k4 * 4];
                acc += wv.x * cv.x + wv.y * cv.y + wv.z * cv.z + wv.w * cv.w;
            }
            p.ws[WS_BV + i] = acc;
        }
        if (tid < 128) partf[tid] += partf[tid + 128];
        __syncthreads();
        if (tid < 64) partf[tid] += partf[tid + 64];
        __syncthreads();
        if (tid == 0) {
            float c = 0.f;
            #pragma unroll
            for (int i = 0; i < 64; ++i) c += partf[i];
            p.ws[WS_C0] = c;
        }
    } else {
        // M tile (validated R12), stored TRANSPOSED: ws[WS_M + i*128 + j]
        compute_wc(p, sA, sB, partf, wcl, tid, false);
        const int mm = bid - 5;
        const int j0 = (mm >> 4) * 16;
        const int i0 = (mm & 15) * 8;
        const int o  = tid & 127;
        const int kh = tid >> 7;
        const int j  = j0 + (o >> 3);
        const int i  = i0 + (o & 7);
        float acc = 0.f;
        const float4* zp = (const float4*)&p.zt_Wo[j * 1024 + kh * 512];
        const float4* pp = (const float4*)&p.px_Wo[i * 1024 + kh * 512];
        #pragma unroll 8
        for (int k4 = 0; k4 < 128; ++k4) {
            const float4 zf = zp[k4];
            const float4 pf = pp[k4];
            const float w = wcl[(kh * 128 + k4) >> 3];
            acc += w * (zf.x * pf.x + zf.y * pf.y + zf.z * pf.z + zf.w * pf.w);
        }
        partf[kh * 128 + o] = acc;
        __syncthreads();
        if (tid < 128) {
            const int jr = j0 + (tid >> 3);
            const int ir = i0 + (tid & 7);
            p.ws[WS_M + ir * 128 + jr] = partf[tid] + partf[128 + tid];
        }
    }
}

__global__ __launch_bounds__(256, 2) void main_kernel(P p) {
    __shared__ unsigned short bufA[32 * 136];   // feat f / u ft
    __shared__ unsigned short bufB[128 * 136];  // feat Wo^T / u Mt then fx
    __shared__ unsigned short bufW[32 * 136];   // u W'
    __shared__ float atl[32];
    const int tid = threadIdx.x;
    const int bid = blockIdx.x;
    const int l   = tid & 63;
    const int wid = tid >> 6;

    if (bid < 384) {
        // ============ feat (R21 MFMA, g from ws) ============
        const bool is_zt = bid >= 128;
        int b, rt, cq;
        if (!is_zt) { b = bid >> 5;             rt = (bid >> 3) & 3;          cq = bid & 7; }
        else        { const int un = bid - 128; b = un >> 6; rt = (un >> 3) & 7; cq = un & 7; }
        const int R   = is_zt ? 256 : 128;
        const int r0g = b * R + rt * 32;
        const int co0 = cq * 128;

        const float* Wx = is_zt ? p.zt_Wx : p.px_Wx;
        const float* bxv = is_zt ? p.zt_bx : p.px_bx;
        const float* Wo = is_zt ? p.zt_Wo : p.px_Wo;
        const float* bo = is_zt ? p.zt_bo : p.px_bo;
        const float* coord = is_zt ? p.t : p.x;
        const float mult = is_zt ? p.zt_mult[0] : p.px_mult[0];
        const float* g = p.ws + (is_zt ? WS_GT : WS_GX) + b * 128;
        float* outp = is_zt ? p.out_zt : p.out_px;

        {
            const int j  = tid & 127;
            const int rh = tid >> 7;
            const float gv = g[j];
            const float wxj = Wx[j], bxj = bxv[j];
            #pragma unroll
            for (int rr = 0; rr < 16; ++rr) {
                const int row = rh * 16 + rr;
                bufA[row * 136 + j] =
                    f2bf(__sinf(coord[r0g + row] * wxj + bxj) * gv);
            }
        }
        #pragma unroll
        for (int i = 0; i < 2; ++i) {
            const int s  = tid + 256 * i;
            const int kt = s >> 5;
            const int ct = s & 31;
            float4 r[8];
            #pragma unroll
            for (int kk = 0; kk < 8; ++kk)
                r[kk] = *(const float4*)&Wo[(kt * 8 + kk) * 1024 + co0 + ct * 4];
            #pragma unroll
            for (int c = 0; c < 4; ++c) {
                short8v o;
                #pragma unroll
                for (int kk = 0; kk < 8; ++kk)
                    o[kk] = (short)f2bf(((const float*)&r[kk])[c]);
                *(short8v*)&bufB[(ct * 4 + c) * 136 + kt * 8] = o;
            }
        }
        __syncthreads();

        f32x4 a00 = {0.f,0.f,0.f,0.f}, a01 = {0.f,0.f,0.f,0.f};
        f32x4 a10 = {0.f,0.f,0.f,0.f}, a11 = {0.f,0.f,0.f,0.f};
        const int rsel = (l & 15) * 136;
        #pragma unroll
        for (int ks = 0; ks < 4; ++ks) {
            const int koff = ks * 32 + (l >> 4) * 8;
            const short8v fa0 = *(const short8v*)&bufA[rsel + koff];
            const short8v fa1 = *(const short8v*)&bufA[16 * 136 + rsel + koff];
            const short8v wb0 = *(const short8v*)&bufB[(wid * 32) * 136 + rsel + koff];
            const short8v wb1 = *(const short8v*)&bufB[(wid * 32 + 16) * 136 + rsel + koff];
            a00 = __builtin_amdgcn_mfma_f32_16x16x32_bf16(fa0, wb0, a00, 0, 0, 0);
            a01 = __builtin_amdgcn_mfma_f32_16x16x32_bf16(fa0, wb1, a01, 0, 0, 0);
            a10 = __builtin_amdgcn_mfma_f32_16x16x32_bf16(fa1, wb0, a10, 0, 0, 0);
            a11 = __builtin_amdgcn_mfma_f32_16x16x32_bf16(fa1, wb1, a11, 0, 0, 0);
        }

        const int crow = (l >> 4) * 4;
        const int ccol = l & 15;
        const int cb   = co0 + wid * 32 + ccol;
        const float b0v = bo[cb];
        const float b1v = bo[cb + 16];
        #pragma unroll
        for (int r = 0; r < 4; ++r) {
            const int ra = (r0g + crow + r) * 1024;
            const int rb = (r0g + 16 + crow + r) * 1024;
            outp[ra + cb]      = mult * (a00[r] + b0v);
            outp[ra + cb + 16] = mult * (a01[r] + b1v);
            outp[rb + cb]      = mult * (a10[r] + b0v);
            outp[rb + cb + 16] = mult * (a11[r] + b1v);
        }
    } else {
        // ============ u via M: two chained MFMA GEMMs ============
        const int m   = bid - 384;          // 0..31
        const int b   = m >> 3;
        const int t0r = (m & 7) * 32;
        const float* gx = p.ws + WS_GX + b * 128;
        const float* gt = p.ws + WS_GT + b * 128;

        // ft -> bufA [32][136]
        {
            const int row = tid >> 3;
            const int j0  = (tid & 7) * 16;
            const float tc = p.t[b * 256 + t0r + row];
            short8v o0, o1;
            #pragma unroll
            for (int q = 0; q < 8; ++q) {
                const int j = j0 + q;
                o0[q] = (short)f2bf(__sinf(tc * p.zt_Wx[j] + p.zt_bx[j]) * gt[j]);
            }
            #pragma unroll
            for (int q = 0; q < 8; ++q) {
                const int j = j0 + 8 + q;
                o1[q] = (short)f2bf(__sinf(tc * p.zt_Wx[j] + p.zt_bx[j]) * gt[j]);
            }
            *(short8v*)&bufA[row * 136 + j0]     = o0;
            *(short8v*)&bufA[row * 136 + j0 + 8] = o1;
        }
        // Mt -> bufB [128][136]
        {
            const int r  = tid >> 1;
            const int h0 = (tid & 1) * 64;
            const float* src = p.ws + WS_M + r * 128 + h0;
            #pragma unroll
            for (int g8 = 0; g8 < 8; ++g8) {
                const float4 v0 = *(const float4*)&src[g8 * 8];
                const float4 v1 = *(const float4*)&src[g8 * 8 + 4];
                short8v o;
                o[0] = (short)f2bf(v0.x); o[1] = (short)f2bf(v0.y);
                o[2] = (short)f2bf(v0.z); o[3] = (short)f2bf(v0.w);
                o[4] = (short)f2bf(v1.x); o[5] = (short)f2bf(v1.y);
                o[6] = (short)f2bf(v1.z); o[7] = (short)f2bf(v1.w);
                *(short8v*)&bufB[r * 136 + h0 + g8 * 8] = o;
            }
        }
        __syncthreads();

        // stage 1: W' = ft @ M + bvec  (acc f32, -> bf16 bufW)
        const int rsel = (l & 15) * 136;
        {
            f32x4 a00 = {0.f,0.f,0.f,0.f}, a01 = {0.f,0.f,0.f,0.f};
            f32x4 a10 = {0.f,0.f,0.f,0.f}, a11 = {0.f,0.f,0.f,0.f};
            #pragma unroll
            for (int ks = 0; ks < 4; ++ks) {
                const int koff = ks * 32 + (l >> 4) * 8;
                const short8v fa0 = *(const short8v*)&bufA[rsel + koff];
                const short8v fa1 = *(const short8v*)&bufA[16 * 136 + rsel + koff];
                const short8v mb0 = *(const short8v*)&bufB[(wid * 32) * 136 + rsel + koff];
                const short8v mb1 = *(const short8v*)&bufB[(wid * 32 + 16) * 136 + rsel + koff];
                a00 = __builtin_amdgcn_mfma_f32_16x16x32_bf16(fa0, mb0, a00, 0, 0, 0);
                a01 = __builtin_amdgcn_mfma_f32_16x16x32_bf16(fa0, mb1, a01, 0, 0, 0);
                a10 = __builtin_amdgcn_mfma_f32_16x16x32_bf16(fa1, mb0, a10, 0, 0, 0);
                a11 = __builtin_amdgcn_mfma_f32_16x16x32_bf16(fa1, mb1, a11, 0, 0, 0);
            }
            const int crow = (l >> 4) * 4;
            const int ccol = l & 15;
            const int cb   = wid * 32 + ccol;
            const float bv0 = p.ws[WS_BV + cb];
            const float bv1 = p.ws[WS_BV + cb + 16];
            #pragma unroll
            for (int r = 0; r < 4; ++r) {
                bufW[(crow + r) * 136 + cb]           = f2bf(a00[r] + bv0);
                bufW[(crow + r) * 136 + cb + 16]      = f2bf(a01[r] + bv1);
                bufW[(16 + crow + r) * 136 + cb]      = f2bf(a10[r] + bv0);
                bufW[(16 + crow + r) * 136 + cb + 16] = f2bf(a11[r] + bv1);
            }
        }
        __syncthreads();   // stage-1 reads of bufB done; bufW visible

        // fx -> bufB [128][136]; at[t] = c0 + ft.a (threads 0..31)
        {
            const int xr = tid >> 1;
            const int jh = (tid & 1) * 64;
            const float xc = p.x[b * 128 + xr];
            #pragma unroll
            for (int g8 = 0; g8 < 8; ++g8) {
                short8v o;
                #pragma unroll
                for (int q = 0; q < 8; ++q) {
                    const int j = jh + g8 * 8 + q;
                    o[q] = (short)f2bf(__sinf(xc * p.px_Wx[j] + p.px_bx[j]) * gx[j]);
                }
                *(short8v*)&bufB[xr * 136 + jh + g8 * 8] = o;
            }
        }
        if (tid < 32) {
            float s = p.ws[WS_C0];
            for (int j = 0; j < 128; ++j)
                s += bf2f(bufA[tid * 136 + j]) * p.ws[WS_A + j];
            atl[tid] = s;
        }
        __syncthreads();

        // stage 2: U = W' @ fx^T
        {
            f32x4 b00 = {0.f,0.f,0.f,0.f}, b01 = {0.f,0.f,0.f,0.f};
            f32x4 b10 = {0.f,0.f,0.f,0.f}, b11 = {0.f,0.f,0.f,0.f};
            #pragma unroll
            for (int ks = 0; ks < 4; ++ks) {
                const int koff = ks * 32 + (l >> 4) * 8;
                const short8v wa0 = *(const short8v*)&bufW[rsel + koff];
                const short8v wa1 = *(const short8v*)&bufW[16 * 136 + rsel + koff];
                const short8v fb0 = *(const short8v*)&bufB[(wid * 32) * 136 + rsel + koff];
                const short8v fb1 = *(const short8v*)&bufB[(wid * 32 + 16) * 136 + rsel + koff];
                b00 = __builtin_amdgcn_mfma_f32_16x16x32_bf16(wa0, fb0, b00, 0, 0, 0);
                b01 = __builtin_amdgcn_mfma_f32_16x16x32_bf16(wa0, fb1, b01, 0, 0, 0);
                b10 = __builtin_amdgcn_mfma_f32_16x16x32_bf16(wa1, fb0, b10, 0, 0, 0);
                b11 = __builtin_amdgcn_mfma_f32_16x16x32_bf16(wa1, fb1, b11, 0, 0, 0);
            }
            const float mzmp = p.zt_mult[0] * p.px_mult[0];
            const float K0 = p.ws[WS_K0];
            const int crow = (l >> 4) * 4;
            const int ccol = l & 15;
            const int xb   = wid * 32 + ccol;
            #pragma unroll
            for (int r = 0; r < 4; ++r) {
                const int ta = t0r + crow + r;
                const int tb = t0r + 16 + crow + r;
                const float ka = K0 + mzmp * atl[crow + r];
                const float kb = K0 + mzmp * atl[16 + crow + r];
                p.out_u[(b * 256 + ta) * 128 + xb]      = ka + mzmp * b00[r];
                p.out_u[(b * 256 + ta) * 128 + xb + 16] = ka + mzmp * b01[r];
                p.out_u[(b * 256 + tb) * 128 + xb]      = kb + mzmp * b10[r];
                p.out_u[(b * 256 + tb) * 128 + xb + 16] = kb + mzmp * b11[r];
            }
        }
    }
}

extern "C" void kernel_launch(void* const* d_in, const int* in_sizes, int n_in,
                              void* d_out, int out_size, void* d_ws, size_t ws_size,
                              hipStream_t stream) {
    float* out = (float*)d_out;

    P prm;
    prm.x       = (const float*)d_in[0];
    prm.t       = (const float*)d_in[1];
    prm.param   = (const float*)d_in[2];
    prm.p2e_W1  = (const float*)d_in[3];
    prm.p2e_b1  = (const float*)d_in[4];
    prm.p2e_W2  = (const float*)d_in[5];
    prm.p2e_b2  = (const float*)d_in[6];
    prm.e2ex_W  = (const float*)d_in[7];
    prm.e2ex_b  = (const float*)d_in[8];
    prm.e2et_W  = (const float*)d_in[9];
    prm.e2et_b  = (const float*)d_in[10];
    prm.px_Wx   = (const float*)d_in[11];
    prm.px_bx   = (const float*)d_in[12];
    prm.px_We   = (const float*)d_in[13];
    prm.px_be   = (const float*)d_in[14];
    prm.px_Wo   = (const float*)d_in[15];
    prm.px_bo   = (const float*)d_in[16];
    prm.px_mult = (const float*)d_in[17];
    prm.zt_Wx   = (const float*)d_in[18];
    prm.zt_bx   = (const float*)d_in[19];
    prm.zt_We   = (const float*)d_in[20];
    prm.zt_be   = (const float*)d_in[21];
    prm.zt_Wo   = (const float*)d_in[22];
    prm.zt_bo   = (const float*)d_in[23];
    prm.zt_mult = (const float*)d_in[24];
    prm.h0      = (const float*)d_in[25];
    prm.blk_W1  = (const float*)d_in[26];
    prm.blk_b1  = (const float*)d_in[27];
    prm.blk_Wc  = (const float*)d_in[28];
    prm.blk_bc  = (const float*)d_in[29];
    prm.blk_W2  = (const float*)d_in[30];
    prm.blk_b2  = (const float*)d_in[31];
    prm.d_W     = (const float*)d_in[32];
    prm.d_b     = (const float*)d_in[33];
    prm.out_u   = out;                        // 131072
    prm.out_zt  = out + 131072;               // 1048576
    prm.out_px  = out + 131072 + 1048576;     // 524288
    prm.ws      = (float*)d_ws;

    prep_kernel<<<133, 256, 0, stream>>>(prm);
    main_kernel<<<416, 256, 0, stream>>>(prm);
}

// Round 23
// 26.689 us; speedup vs baseline: 1.8807x; 1.8807x over previous
//
#include <hip/hip_runtime.h>
#include <math.h>

// B=4, X=128, T=256, HIDDEN=128, EMB=128, DH=32, LATENT=32, K=1024
// Outputs concat: u (131072), zt (1048576), px (524288)
// u[b,t,x] = K0 + sum_k zt[b,t,k]*px[b,x,k]*wc[k>>5]   (wc = wcd/32)
//
// R23 = R21 (validated 23.7us) with u grid split 256 -> 512 blocks
// (x-tile 32 -> 16) for 2 blocks/CU latency overlap. Numerics identical.

typedef __attribute__((ext_vector_type(8))) short short8v;   // 8 bf16
typedef __attribute__((ext_vector_type(4))) float f32x4;

struct P {
    const float *x, *t, *param;
    const float *p2e_W1, *p2e_b1, *p2e_W2, *p2e_b2;
    const float *e2ex_W, *e2ex_b, *e2et_W, *e2et_b;
    const float *px_Wx, *px_bx, *px_We, *px_be, *px_Wo, *px_bo, *px_mult;
    const float *zt_Wx, *zt_bx, *zt_We, *zt_be, *zt_Wo, *zt_bo, *zt_mult;
    const float *h0, *blk_W1, *blk_b1, *blk_Wc, *blk_bc, *blk_W2, *blk_b2;
    const float *d_W, *d_b;
    float *out_u, *out_zt, *out_px, *ws;
};

__device__ __forceinline__ void fma4(float4& a, float s, const float4& v) {
    a.x += s * v.x; a.y += s * v.y; a.z += s * v.z; a.w += s * v.w;
}

__device__ __forceinline__ unsigned short f2bf(float f) {
    unsigned int u = __float_as_uint(f);
    return (unsigned short)((u + 0x7FFFu + ((u >> 16) & 1u)) >> 16);
}

// out[j] = bias[j] + sum_k vin[k] * W[k*128+j]; 256 threads. (R11 validated)
__device__ __forceinline__ void gemv_stage(
    const float* __restrict__ W, const float* __restrict__ bias,
    const float* vin, float* vout, float* partf, int tid)
{
    const int j4 = tid & 31;
    const int sl = tid >> 5;
    float4 a4 = make_float4(0.f, 0.f, 0.f, 0.f);
    const float* Wp = W + sl * 16 * 128 + j4 * 4;
    #pragma unroll
    for (int k = 0; k < 16; ++k)
        fma4(a4, vin[sl * 16 + k], *(const float4*)&Wp[k * 128]);
    *(float4*)&partf[sl * 128 + j4 * 4] = a4;
    __syncthreads();
    if (tid < 128) {
        float v = bias[tid];
        #pragma unroll
        for (int q = 0; q < 8; ++q) v += partf[q * 128 + tid];
        vout[tid] = v;
    }
    __syncthreads();
}

__global__ __launch_bounds__(256, 2) void feat_kernel(P p) {
    __shared__ float vin[128], vout[128];
    __shared__ float partf[1024];
    __shared__ unsigned short fbf[32 * 136];    // f bf16, row stride 136
    __shared__ unsigned short wot[128 * 136];   // Wo^T bf16 [c][k]
    const int tid = threadIdx.x;
    const int bid = blockIdx.x;

    if (bid < 384) {
        const bool is_zt = bid >= 128;
        int b, rt, cq;
        if (!is_zt) { b = bid >> 5;          rt = (bid >> 3) & 3;          cq = bid & 7; }
        else        { const int un = bid - 128; b = un >> 6; rt = (un >> 3) & 7; cq = un & 7; }
        const int R   = is_zt ? 256 : 128;
        const int r0g = b * R + rt * 32;     // global row base
        const int co0 = cq * 128;

        const float* Wh = is_zt ? p.e2et_W : p.e2ex_W;
        const float* bh = is_zt ? p.e2et_b : p.e2ex_b;
        const float* We = is_zt ? p.zt_We : p.px_We;
        const float* be = is_zt ? p.zt_be : p.px_be;
        const float* Wx = is_zt ? p.zt_Wx : p.px_Wx;
        const float* bxv = is_zt ? p.zt_bx : p.px_bx;
        const float* Wo = is_zt ? p.zt_Wo : p.px_Wo;
        const float* bo = is_zt ? p.zt_bo : p.px_bo;
        const float* coord = is_zt ? p.t : p.x;
        const float mult = is_zt ? p.zt_mult[0] : p.px_mult[0];
        float* outp = is_zt ? p.out_zt : p.out_px;

        // ---- g-chain (R11 validated) ----
        if (tid < 128) {
            float a = p.p2e_b1[tid];
            #pragma unroll
            for (int q = 0; q < 16; ++q)
                a += p.param[b * 16 + q] * p.p2e_W1[q * 128 + tid];
            vin[tid] = __sinf(a);
        }
        __syncthreads();
        gemv_stage(p.p2e_W2, p.p2e_b2, vin, vout, partf, tid);   // e
        gemv_stage(Wh, bh, vout, vin, partf, tid);               // ex/et
        gemv_stage(We, be, vin, vout, partf, tid);               // g in vout

        // ---- f rows -> bf16 LDS [32][136] ----
        {
            const int j  = tid & 127;
            const int rh = tid >> 7;
            const float g = vout[j];
            const float wxj = Wx[j], bxj = bxv[j];
            #pragma unroll
            for (int rr = 0; rr < 16; ++rr) {
                const int row = rh * 16 + rr;
                fbf[row * 136 + j] =
                    f2bf(__sinf(coord[r0g + row] * wxj + bxj) * g);
            }
        }

        // ---- stage Wo^T tile: 128k x 128c -> wot[c][k] bf16 ----
        #pragma unroll
        for (int i = 0; i < 2; ++i) {
            const int s  = tid + 256 * i;    // 0..511
            const int kt = s >> 5;           // 0..15 (8-k group)
            const int ct = s & 31;           // 0..31 (4-c group)
            float4 r[8];
            #pragma unroll
            for (int kk = 0; kk < 8; ++kk)
                r[kk] = *(const float4*)&Wo[(kt * 8 + kk) * 1024 + co0 + ct * 4];
            #pragma unroll
            for (int c = 0; c < 4; ++c) {
                short8v o;
                #pragma unroll
                for (int kk = 0; kk < 8; ++kk)
                    o[kk] = (short)f2bf(((const float*)&r[kk])[c]);
                *(short8v*)&wot[(ct * 4 + c) * 136 + kt * 8] = o;
            }
        }
        __syncthreads();

        // ---- MFMA: C[32x128]; wave wid -> cols wid*32..wid*32+31 ----
        const int l   = tid & 63;
        const int wid = tid >> 6;
        f32x4 a00 = {0.f,0.f,0.f,0.f}, a01 = {0.f,0.f,0.f,0.f};
        f32x4 a10 = {0.f,0.f,0.f,0.f}, a11 = {0.f,0.f,0.f,0.f};
        const int rsel = (l & 15) * 136;
        #pragma unroll
        for (int ks = 0; ks < 4; ++ks) {
            const int koff = ks * 32 + (l >> 4) * 8;
            const short8v fa0 = *(const short8v*)&fbf[rsel + koff];
            const short8v fa1 = *(const short8v*)&fbf[16 * 136 + rsel + koff];
            const short8v wb0 = *(const short8v*)&wot[(wid * 32) * 136 + rsel + koff];
            const short8v wb1 = *(const short8v*)&wot[(wid * 32 + 16) * 136 + rsel + koff];
            a00 = __builtin_amdgcn_mfma_f32_16x16x32_bf16(fa0, wb0, a00, 0, 0, 0);
            a01 = __builtin_amdgcn_mfma_f32_16x16x32_bf16(fa0, wb1, a01, 0, 0, 0);
            a10 = __builtin_amdgcn_mfma_f32_16x16x32_bf16(fa1, wb0, a10, 0, 0, 0);
            a11 = __builtin_amdgcn_mfma_f32_16x16x32_bf16(fa1, wb1, a11, 0, 0, 0);
        }

        const int crow = (l >> 4) * 4;
        const int ccol = l & 15;
        const int cb   = co0 + wid * 32 + ccol;
        const float b0v = bo[cb];
        const float b1v = bo[cb + 16];
        #pragma unroll
        for (int r = 0; r < 4; ++r) {
            const int ra = (r0g + crow + r) * 1024;
            const int rb = (r0g + 16 + crow + r) * 1024;
            outp[ra + cb]      = mult * (a00[r] + b0v);
            outp[ra + cb + 16] = mult * (a01[r] + b1v);
            outp[rb + cb]      = mult * (a10[r] + b0v);
            outp[rb + cb + 16] = mult * (a11[r] + b1v);
        }
    } else {
        // constants -> ws[0..31]=wc, ws[32]=K0 (R11 validated)
        __shared__ float dws[128];
        if (tid < 128) { vin[tid] = p.h0[tid]; dws[tid] = p.d_W[tid]; }
        __syncthreads();
        gemv_stage(p.blk_W1, p.blk_b1, vin, vout, partf, tid);   // sacc
        if (tid < 128) {
            float w2 = 0.f;
            const float4* rp = (const float4*)&p.blk_W2[tid * 128];
            #pragma unroll
            for (int m4 = 0; m4 < 32; ++m4) {
                const float4 wv = rp[m4];
                const float4 dv = *(const float4*)&dws[m4 * 4];
                w2 += wv.x * dv.x + wv.y * dv.y + wv.z * dv.z + wv.w * dv.w;
            }
            const float sv = __sinf(vout[tid]) * w2;
            vin[tid] = sv;
            vout[tid] = (p.h0[tid] + p.blk_b2[tid]) * dws[tid] + sv * p.blk_bc[tid];
        }
        __syncthreads();
        {
            const int d  = tid >> 3;
            const int sg = (tid & 7) * 16;
            float acc = 0.f;
            #pragma unroll
            for (int i4 = 0; i4 < 4; ++i4) {
                const float4 wv = *(const float4*)&p.blk_Wc[d * 128 + sg + i4 * 4];
                const float4 sv = *(const float4*)&vin[sg + i4 * 4];
                acc += wv.x * sv.x + wv.y * sv.y + wv.z * sv.z + wv.w * sv.w;
            }
            partf[d * 8 + (tid & 7)] = acc;
        }
        __syncthreads();
        if (tid < 32) {
            float w = 0.f;
            #pragma unroll
            for (int q = 0; q < 8; ++q) w += partf[tid * 8 + q];
            p.ws[tid] = w * (1.0f / 32.0f);
        }
        if (tid < 64) vout[tid] += vout[tid + 64];
        __syncthreads();
        if (tid == 0) {
            float K = p.d_b[0];
            #pragma unroll
            for (int i = 0; i < 64; ++i) K += vout[i];
            p.ws[32] = K;
        }
    }
}

// MFMA u: 512 blocks = 4b x 16 t-tiles(16) x 8 x-eighths(16). 256 thr.
// Per block: 16 t-rows x 16 x-cols; 2 blocks/CU for latency overlap.
__global__ __launch_bounds__(256) void u_kernel(
    const float* __restrict__ zt, const float* __restrict__ px,
    const float* __restrict__ ws, float* __restrict__ out_u)
{
    __shared__ unsigned short ztbf[16 * 536];
    __shared__ unsigned short pxbf[16 * 536];
    __shared__ float red[4 * 256];
    __shared__ float wcs[32];
    __shared__ float K0s;

    const int tid = threadIdx.x;
    const int bid = blockIdx.x;
    const int b   = bid >> 7;
    const int rem = bid & 127;
    const int t0  = (rem >> 3) * 16;
    const int x0  = (rem & 7) * 16;

    if (tid < 32) wcs[tid] = ws[tid];
    if (tid == 32) K0s = ws[32];

    const float* ztb = zt + (b * 256 + t0) * 1024;
    const float* pxb = px + (b * 128 + x0) * 1024;
    const int l   = tid & 63;
    const int wid = tid >> 6;

    f32x4 acc0 = {0.f, 0.f, 0.f, 0.f};

    __syncthreads();   // wcs/K0s visible

    for (int h = 0; h < 2; ++h) {
        const int kb = h * 512;
        if (h) __syncthreads();   // previous MFMA reads complete

        // stage zt half: 16 rows x 512 -> 1024 short8 chunks (4/thread)
        #pragma unroll
        for (int i = 0; i < 4; ++i) {
            const int s   = tid + 256 * i;
            const int row = s >> 6;
            const int kc8 = (s & 63) * 8;
            const float* src = ztb + row * 1024 + kb + kc8;
            const float4 v0 = *(const float4*)src;
            const float4 v1 = *(const float4*)(src + 4);
            short8v o;
            o[0] = (short)f2bf(v0.x); o[1] = (short)f2bf(v0.y);
            o[2] = (short)f2bf(v0.z); o[3] = (short)f2bf(v0.w);
            o[4] = (short)f2bf(v1.x); o[5] = (short)f2bf(v1.y);
            o[6] = (short)f2bf(v1.z); o[7] = (short)f2bf(v1.w);
            *(short8v*)&ztbf[row * 536 + kc8] = o;
        }
        // stage px half (scaled by wc): 16 rows x 512 (4/thread)
        #pragma unroll
        for (int i = 0; i < 4; ++i) {
            const int s   = tid + 256 * i;
            const int row = s >> 6;
            const int kc8 = (s & 63) * 8;
            const float sc = wcs[(kb + kc8) >> 5];
            const float* src = pxb + row * 1024 + kb + kc8;
            const float4 v0 = *(const float4*)src;
            const float4 v1 = *(const float4*)(src + 4);
            short8v o;
            o[0] = (short)f2bf(sc * v0.x); o[1] = (short)f2bf(sc * v0.y);
            o[2] = (short)f2bf(sc * v0.z); o[3] = (short)f2bf(sc * v0.w);
            o[4] = (short)f2bf(sc * v1.x); o[5] = (short)f2bf(sc * v1.y);
            o[6] = (short)f2bf(sc * v1.z); o[7] = (short)f2bf(sc * v1.w);
            *(short8v*)&pxbf[row * 536 + kc8] = o;
        }
        __syncthreads();

        // MFMA: wave k-slice = wid*128 within this half; 4 k-steps x 1 x-tile
        const int rsel = (l & 15) * 536;
        #pragma unroll
        for (int ks = 0; ks < 4; ++ks) {
            const int kloc = wid * 128 + ks * 32 + (l >> 4) * 8;
            const short8v a  = *(const short8v*)&ztbf[rsel + kloc];
            const short8v b0 = *(const short8v*)&pxbf[rsel + kloc];
            acc0 = __builtin_amdgcn_mfma_f32_16x16x32_bf16(a, b0, acc0, 0, 0, 0);
        }
    }

    // write partials
    #pragma unroll
    for (int r = 0; r < 4; ++r)
        red[wid * 256 + l * 4 + r] = acc0[r];
    __syncthreads();

    // reduce + write: thread p -> lane ll=(p&63), reg rr=(p>>6).
    {
        const int ll = tid & 63;
        const int rr = tid >> 6;
        const int ri = ll * 4 + rr;
        const int tt = t0 + ((ll >> 4) << 2) + rr;
        float sum = K0s;
        #pragma unroll
        for (int w = 0; w < 4; ++w) sum += red[w * 256 + ri];
        const int xx = x0 + (ll & 15);
        out_u[(b * 256 + tt) * 128 + xx] = sum;
    }
}

extern "C" void kernel_launch(void* const* d_in, const int* in_sizes, int n_in,
                              void* d_out, int out_size, void* d_ws, size_t ws_size,
                              hipStream_t stream) {
    float* out = (float*)d_out;
    float* ws  = (float*)d_ws;

    P prm;
    prm.x       = (const float*)d_in[0];
    prm.t       = (const float*)d_in[1];
    prm.param   = (const float*)d_in[2];
    prm.p2e_W1  = (const float*)d_in[3];
    prm.p2e_b1  = (const float*)d_in[4];
    prm.p2e_W2  = (const float*)d_in[5];
    prm.p2e_b2  = (const float*)d_in[6];
    prm.e2ex_W  = (const float*)d_in[7];
    prm.e2ex_b  = (const float*)d_in[8];
    prm.e2et_W  = (const float*)d_in[9];
    prm.e2et_b  = (const float*)d_in[10];
    prm.px_Wx   = (const float*)d_in[11];
    prm.px_bx   = (const float*)d_in[12];
    prm.px_We   = (const float*)d_in[13];
    prm.px_be   = (const float*)d_in[14];
    prm.px_Wo   = (const float*)d_in[15];
    prm.px_bo   = (const float*)d_in[16];
    prm.px_mult = (const float*)d_in[17];
    prm.zt_Wx   = (const float*)d_in[18];
    prm.zt_bx   = (const float*)d_in[19];
    prm.zt_We   = (const float*)d_in[20];
    prm.zt_be   = (const float*)d_in[21];
    prm.zt_Wo   = (const float*)d_in[22];
    prm.zt_bo   = (const float*)d_in[23];
    prm.zt_mult = (const float*)d_in[24];
    prm.h0      = (const float*)d_in[25];
    prm.blk_W1  = (const float*)d_in[26];
    prm.blk_b1  = (const float*)d_in[27];
    prm.blk_Wc  = (const float*)d_in[28];
    prm.blk_bc  = (const float*)d_in[29];
    prm.blk_W2  = (const float*)d_in[30];
    prm.blk_b2  = (const float*)d_in[31];
    prm.d_W     = (const float*)d_in[32];
    prm.d_b     = (const float*)d_in[33];
    prm.out_u   = out;                        // 131072
    prm.out_zt  = out + 131072;               // 1048576
    prm.out_px  = out + 131072 + 1048576;     // 524288
    prm.ws      = ws;

    feat_kernel<<<385, 256, 0, stream>>>(prm);
    u_kernel<<<512, 256, 0, stream>>>(prm.out_zt, prm.out_px, ws, out);
}

// Round 24
// 19.683 us; speedup vs baseline: 2.5502x; 1.3560x over previous
//
#include <hip/hip_runtime.h>
#include <math.h>

// B=4, X=128, T=256, HIDDEN=128, EMB=128, DH=32, LATENT=32, K=1024
// Outputs concat: u (131072), zt (1048576), px (524288)
// u[b,t,x] = K0 + sum_k zt[b,t,k]*px[b,x,k]*wc[k>>5]   (wc = wcd/32)
//
// R24 = R21 + bf16 side-band: feat writes bf16 copies of zt/px into ws;
// u stages bf16 directly (half the L3 bytes, no conversions in u) and applies
// wc per K=32 MFMA group in f32. Fallback to R21's u if ws too small.
// ws: [0..31] wc, [32] K0, [64..) zt_bf (1048576 shorts), px_bf (524288).

typedef __attribute__((ext_vector_type(8))) short short8v;   // 8 bf16
typedef __attribute__((ext_vector_type(4))) float f32x4;

struct P {
    const float *x, *t, *param;
    const float *p2e_W1, *p2e_b1, *p2e_W2, *p2e_b2;
    const float *e2ex_W, *e2ex_b, *e2et_W, *e2et_b;
    const float *px_Wx, *px_bx, *px_We, *px_be, *px_Wo, *px_bo, *px_mult;
    const float *zt_Wx, *zt_bx, *zt_We, *zt_be, *zt_Wo, *zt_bo, *zt_mult;
    const float *h0, *blk_W1, *blk_b1, *blk_Wc, *blk_bc, *blk_W2, *blk_b2;
    const float *d_W, *d_b;
    float *out_u, *out_zt, *out_px, *ws;
    unsigned short *ztbf_g, *pxbf_g;    // bf16 side-band (null if ws small)
};

__device__ __forceinline__ void fma4(float4& a, float s, const float4& v) {
    a.x += s * v.x; a.y += s * v.y; a.z += s * v.z; a.w += s * v.w;
}

__device__ __forceinline__ unsigned short f2bf(float f) {
    unsigned int u = __float_as_uint(f);
    return (unsigned short)((u + 0x7FFFu + ((u >> 16) & 1u)) >> 16);
}

// out[j] = bias[j] + sum_k vin[k] * W[k*128+j]; 256 threads. (R11 validated)
__device__ __forceinline__ void gemv_stage(
    const float* __restrict__ W, const float* __restrict__ bias,
    const float* vin, float* vout, float* partf, int tid)
{
    const int j4 = tid & 31;
    const int sl = tid >> 5;
    float4 a4 = make_float4(0.f, 0.f, 0.f, 0.f);
    const float* Wp = W + sl * 16 * 128 + j4 * 4;
    #pragma unroll
    for (int k = 0; k < 16; ++k)
        fma4(a4, vin[sl * 16 + k], *(const float4*)&Wp[k * 128]);
    *(float4*)&partf[sl * 128 + j4 * 4] = a4;
    __syncthreads();
    if (tid < 128) {
        float v = bias[tid];
        #pragma unroll
        for (int q = 0; q < 8; ++q) v += partf[q * 128 + tid];
        vout[tid] = v;
    }
    __syncthreads();
}

__global__ __launch_bounds__(256, 2) void feat_kernel(P p) {
    __shared__ float vin[128], vout[128];
    __shared__ float partf[1024];
    __shared__ unsigned short fbf[32 * 136];
    __shared__ unsigned short wot[128 * 136];
    const int tid = threadIdx.x;
    const int bid = blockIdx.x;

    if (bid < 384) {
        const bool is_zt = bid >= 128;
        int b, rt, cq;
        if (!is_zt) { b = bid >> 5;          rt = (bid >> 3) & 3;          cq = bid & 7; }
        else        { const int un = bid - 128; b = un >> 6; rt = (un >> 3) & 7; cq = un & 7; }
        const int R   = is_zt ? 256 : 128;
        const int r0g = b * R + rt * 32;
        const int co0 = cq * 128;

        const float* Wh = is_zt ? p.e2et_W : p.e2ex_W;
        const float* bh = is_zt ? p.e2et_b : p.e2ex_b;
        const float* We = is_zt ? p.zt_We : p.px_We;
        const float* be = is_zt ? p.zt_be : p.px_be;
        const float* Wx = is_zt ? p.zt_Wx : p.px_Wx;
        const float* bxv = is_zt ? p.zt_bx : p.px_bx;
        const float* Wo = is_zt ? p.zt_Wo : p.px_Wo;
        const float* bo = is_zt ? p.zt_bo : p.px_bo;
        const float* coord = is_zt ? p.t : p.x;
        const float mult = is_zt ? p.zt_mult[0] : p.px_mult[0];
        float* outp = is_zt ? p.out_zt : p.out_px;
        unsigned short* obf = is_zt ? p.ztbf_g : p.pxbf_g;

        // ---- g-chain (R11 validated) ----
        if (tid < 128) {
            float a = p.p2e_b1[tid];
            #pragma unroll
            for (int q = 0; q < 16; ++q)
                a += p.param[b * 16 + q] * p.p2e_W1[q * 128 + tid];
            vin[tid] = __sinf(a);
        }
        __syncthreads();
        gemv_stage(p.p2e_W2, p.p2e_b2, vin, vout, partf, tid);   // e
        gemv_stage(Wh, bh, vout, vin, partf, tid);               // ex/et
        gemv_stage(We, be, vin, vout, partf, tid);               // g in vout

        {
            const int j  = tid & 127;
            const int rh = tid >> 7;
            const float g = vout[j];
            const float wxj = Wx[j], bxj = bxv[j];
            #pragma unroll
            for (int rr = 0; rr < 16; ++rr) {
                const int row = rh * 16 + rr;
                fbf[row * 136 + j] =
                    f2bf(__sinf(coord[r0g + row] * wxj + bxj) * g);
            }
        }

        #pragma unroll
        for (int i = 0; i < 2; ++i) {
            const int s  = tid + 256 * i;
            const int kt = s >> 5;
            const int ct = s & 31;
            float4 r[8];
            #pragma unroll
            for (int kk = 0; kk < 8; ++kk)
                r[kk] = *(const float4*)&Wo[(kt * 8 + kk) * 1024 + co0 + ct * 4];
            #pragma unroll
            for (int c = 0; c < 4; ++c) {
                short8v o;
                #pragma unroll
                for (int kk = 0; kk < 8; ++kk)
                    o[kk] = (short)f2bf(((const float*)&r[kk])[c]);
                *(short8v*)&wot[(ct * 4 + c) * 136 + kt * 8] = o;
            }
        }
        __syncthreads();

        const int l   = tid & 63;
        const int wid = tid >> 6;
        f32x4 a00 = {0.f,0.f,0.f,0.f}, a01 = {0.f,0.f,0.f,0.f};
        f32x4 a10 = {0.f,0.f,0.f,0.f}, a11 = {0.f,0.f,0.f,0.f};
        const int rsel = (l & 15) * 136;
        #pragma unroll
        for (int ks = 0; ks < 4; ++ks) {
            const int koff = ks * 32 + (l >> 4) * 8;
            const short8v fa0 = *(const short8v*)&fbf[rsel + koff];
            const short8v fa1 = *(const short8v*)&fbf[16 * 136 + rsel + koff];
            const short8v wb0 = *(const short8v*)&wot[(wid * 32) * 136 + rsel + koff];
            const short8v wb1 = *(const short8v*)&wot[(wid * 32 + 16) * 136 + rsel + koff];
            a00 = __builtin_amdgcn_mfma_f32_16x16x32_bf16(fa0, wb0, a00, 0, 0, 0);
            a01 = __builtin_amdgcn_mfma_f32_16x16x32_bf16(fa0, wb1, a01, 0, 0, 0);
            a10 = __builtin_amdgcn_mfma_f32_16x16x32_bf16(fa1, wb0, a10, 0, 0, 0);
            a11 = __builtin_amdgcn_mfma_f32_16x16x32_bf16(fa1, wb1, a11, 0, 0, 0);
        }

        const int crow = (l >> 4) * 4;
        const int ccol = l & 15;
        const int cb   = co0 + wid * 32 + ccol;
        const float b0v = bo[cb];
        const float b1v = bo[cb + 16];
        #pragma unroll
        for (int r = 0; r < 4; ++r) {
            const int ra = (r0g + crow + r) * 1024;
            const int rb = (r0g + 16 + crow + r) * 1024;
            const float v00 = mult * (a00[r] + b0v);
            const float v01 = mult * (a01[r] + b1v);
            const float v10 = mult * (a10[r] + b0v);
            const float v11 = mult * (a11[r] + b1v);
            outp[ra + cb]      = v00;
            outp[ra + cb + 16] = v01;
            outp[rb + cb]      = v10;
            outp[rb + cb + 16] = v11;
            if (obf) {
                obf[ra + cb]      = f2bf(v00);
                obf[ra + cb + 16] = f2bf(v01);
                obf[rb + cb]      = f2bf(v10);
                obf[rb + cb + 16] = f2bf(v11);
            }
        }
    } else {
        // constants -> ws[0..31]=wc, ws[32]=K0 (R11 validated)
        __shared__ float dws[128];
        if (tid < 128) { vin[tid] = p.h0[tid]; dws[tid] = p.d_W[tid]; }
        __syncthreads();
        gemv_stage(p.blk_W1, p.blk_b1, vin, vout, partf, tid);   // sacc
        if (tid < 128) {
            float w2 = 0.f;
            const float4* rp = (const float4*)&p.blk_W2[tid * 128];
            #pragma unroll
            for (int m4 = 0; m4 < 32; ++m4) {
                const float4 wv = rp[m4];
                const float4 dv = *(const float4*)&dws[m4 * 4];
                w2 += wv.x * dv.x + wv.y * dv.y + wv.z * dv.z + wv.w * dv.w;
            }
            const float sv = __sinf(vout[tid]) * w2;
            vin[tid] = sv;
            vout[tid] = (p.h0[tid] + p.blk_b2[tid]) * dws[tid] + sv * p.blk_bc[tid];
        }
        __syncthreads();
        {
            const int d  = tid >> 3;
            const int sg = (tid & 7) * 16;
            float acc = 0.f;
            #pragma unroll
            for (int i4 = 0; i4 < 4; ++i4) {
                const float4 wv = *(const float4*)&p.blk_Wc[d * 128 + sg + i4 * 4];
                const float4 sv = *(const float4*)&vin[sg + i4 * 4];
                acc += wv.x * sv.x + wv.y * sv.y + wv.z * sv.z + wv.w * sv.w;
            }
            partf[d * 8 + (tid & 7)] = acc;
        }
        __syncthreads();
        if (tid < 32) {
            float w = 0.f;
            #pragma unroll
            for (int q = 0; q < 8; ++q) w += partf[tid * 8 + q];
            p.ws[tid] = w * (1.0f / 32.0f);
        }
        if (tid < 64) vout[tid] += vout[tid + 64];
        __syncthreads();
        if (tid == 0) {
            float K = p.d_b[0];
            #pragma unroll
            for (int i = 0; i < 64; ++i) K += vout[i];
            p.ws[32] = K;
        }
    }
}

// bf16-path u: 256 blocks = 4b x 16 t-tiles(16) x 4 x-quarters(32). 256 thr.
// Stages bf16 copies (half bytes, zero conversions); wc applied per K=32
// MFMA group in f32: acc += wc[d] * mfma(a, b, 0).
__global__ __launch_bounds__(256) void u_bf_kernel(
    const unsigned short* __restrict__ ztg, const unsigned short* __restrict__ pxg,
    const float* __restrict__ ws, float* __restrict__ out_u)
{
    __shared__ unsigned short ztbf[16 * 536];
    __shared__ unsigned short pxbf[32 * 536];
    __shared__ float red[4 * 2 * 256];
    __shared__ float wcs[32];
    __shared__ float K0s;

    const int tid = threadIdx.x;
    const int bid = blockIdx.x;
    const int b   = bid >> 6;
    const int rem = bid & 63;
    const int t0  = (rem >> 2) * 16;
    const int x0  = (rem & 3) * 32;

    if (tid < 32) wcs[tid] = ws[tid];
    if (tid == 32) K0s = ws[32];

    const unsigned short* ztb = ztg + (b * 256 + t0) * 1024;
    const unsigned short* pxb = pxg + (b * 128 + x0) * 1024;
    const int l   = tid & 63;
    const int wid = tid >> 6;

    f32x4 acc0 = {0.f, 0.f, 0.f, 0.f};
    f32x4 acc1 = {0.f, 0.f, 0.f, 0.f};

    __syncthreads();

    for (int h = 0; h < 2; ++h) {
        const int kb = h * 512;
        if (h) __syncthreads();

        // stage zt half: 16 rows x 512 shorts -> 1024 short8 (4/thread)
        #pragma unroll
        for (int i = 0; i < 4; ++i) {
            const int s   = tid + 256 * i;
            const int row = s >> 6;
            const int kc8 = (s & 63) * 8;
            *(short8v*)&ztbf[row * 536 + kc8] =
                *(const short8v*)&ztb[row * 1024 + kb + kc8];
        }
        // stage px half: 32 rows x 512 shorts (8/thread), unscaled
        #pragma unroll
        for (int i = 0; i < 8; ++i) {
            const int s   = tid + 256 * i;
            const int row = s >> 6;
            const int kc8 = (s & 63) * 8;
            *(short8v*)&pxbf[row * 536 + kc8] =
                *(const short8v*)&pxb[row * 1024 + kb + kc8];
        }
        __syncthreads();

        const int rsel = (l & 15) * 536;
        #pragma unroll
        for (int ks = 0; ks < 4; ++ks) {
            const int kloc = wid * 128 + ks * 32 + (l >> 4) * 8;
            const float w = wcs[h * 16 + wid * 4 + ks];
            const short8v a  = *(const short8v*)&ztbf[rsel + kloc];
            const short8v b0 = *(const short8v*)&pxbf[rsel + kloc];
            const short8v b1 = *(const short8v*)&pxbf[rsel + 16 * 536 + kloc];
            const f32x4 z = {0.f, 0.f, 0.f, 0.f};
            const f32x4 t0v = __builtin_amdgcn_mfma_f32_16x16x32_bf16(a, b0, z, 0, 0, 0);
            const f32x4 t1v = __builtin_amdgcn_mfma_f32_16x16x32_bf16(a, b1, z, 0, 0, 0);
            #pragma unroll
            for (int r = 0; r < 4; ++r) {
                acc0[r] += w * t0v[r];
                acc1[r] += w * t1v[r];
            }
        }
    }

    #pragma unroll
    for (int r = 0; r < 4; ++r) {
        red[(wid * 2 + 0) * 256 + l * 4 + r] = acc0[r];
        red[(wid * 2 + 1) * 256 + l * 4 + r] = acc1[r];
    }
    __syncthreads();

    {
        const int ll = tid & 63;
        const int rr = tid >> 6;
        const int ri = ll * 4 + rr;
        const int tt = t0 + ((ll >> 4) << 2) + rr;
        #pragma unroll
        for (int xt = 0; xt < 2; ++xt) {
            float sum = K0s;
            #pragma unroll
            for (int w = 0; w < 4; ++w) sum += red[(w * 2 + xt) * 256 + ri];
            const int xx = x0 + xt * 16 + (ll & 15);
            out_u[(b * 256 + tt) * 128 + xx] = sum;
        }
    }
}

// Fallback u (R21/R20 verbatim, f32 inputs): 256 blocks x 256 thr.
__global__ __launch_bounds__(256) void u_kernel(
    const float* __restrict__ zt, const float* __restrict__ px,
    const float* __restrict__ ws, float* __restrict__ out_u)
{
    __shared__ unsigned short ztbf[16 * 536];
    __shared__ unsigned short pxbf[32 * 536];
    __shared__ float red[4 * 2 * 256];
    __shared__ float wcs[32];
    __shared__ float K0s;

    const int tid = threadIdx.x;
    const int bid = blockIdx.x;
    const int b   = bid >> 6;
    const int rem = bid & 63;
    const int t0  = (rem >> 2) * 16;
    const int x0  = (rem & 3) * 32;

    if (tid < 32) wcs[tid] = ws[tid];
    if (tid == 32) K0s = ws[32];

    const float* ztb = zt + (b * 256 + t0) * 1024;
    const float* pxb = px + (b * 128 + x0) * 1024;
    const int l   = tid & 63;
    const int wid = tid >> 6;

    f32x4 acc0 = {0.f, 0.f, 0.f, 0.f};
    f32x4 acc1 = {0.f, 0.f, 0.f, 0.f};

    __syncthreads();

    for (int h = 0; h < 2; ++h) {
        const int kb = h * 512;
        if (h) __syncthreads();

        #pragma unroll
        for (int i = 0; i < 4; ++i) {
            const int s   = tid + 256 * i;
            const int row = s >> 6;
            const int kc8 = (s & 63) * 8;
            const float* src = ztb + row * 1024 + kb + kc8;
            const float4 v0 = *(const float4*)src;
            const float4 v1 = *(const float4*)(src + 4);
            short8v o;
            o[0] = (short)f2bf(v0.x); o[1] = (short)f2bf(v0.y);
            o[2] = (short)f2bf(v0.z); o[3] = (short)f2bf(v0.w);
            o[4] = (short)f2bf(v1.x); o[5] = (short)f2bf(v1.y);
            o[6] = (short)f2bf(v1.z); o[7] = (short)f2bf(v1.w);
            *(short8v*)&ztbf[row * 536 + kc8] = o;
        }
        #pragma unroll
        for (int i = 0; i < 8; ++i) {
            const int s   = tid + 256 * i;
            const int row = s >> 6;
            const int kc8 = (s & 63) * 8;
            const float sc = wcs[(kb + kc8) >> 5];
            const float* src = pxb + row * 1024 + kb + kc8;
            const float4 v0 = *(const float4*)src;
            const float4 v1 = *(const float4*)(src + 4);
            short8v o;
            o[0] = (short)f2bf(sc * v0.x); o[1] = (short)f2bf(sc * v0.y);
            o[2] = (short)f2bf(sc * v0.z); o[3] = (short)f2bf(sc * v0.w);
            o[4] = (short)f2bf(sc * v1.x); o[5] = (short)f2bf(sc * v1.y);
            o[6] = (short)f2bf(sc * v1.z); o[7] = (short)f2bf(sc * v1.w);
            *(short8v*)&pxbf[row * 536 + kc8] = o;
        }
        __syncthreads();

        const int rsel = (l & 15) * 536;
        #pragma unroll
        for (int ks = 0; ks < 4; ++ks) {
            const int kloc = wid * 128 + ks * 32 + (l >> 4) * 8;
            const short8v a  = *(const short8v*)&ztbf[rsel + kloc];
            const short8v b0 = *(const short8v*)&pxbf[rsel + kloc];
            const short8v b1 = *(const short8v*)&pxbf[rsel + 16 * 536 + kloc];
            acc0 = __builtin_amdgcn_mfma_f32_16x16x32_bf16(a, b0, acc0, 0, 0, 0);
            acc1 = __builtin_amdgcn_mfma_f32_16x16x32_bf16(a, b1, acc1, 0, 0, 0);
        }
    }

    #pragma unroll
    for (int r = 0; r < 4; ++r) {
        red[(wid * 2 + 0) * 256 + l * 4 + r] = acc0[r];
        red[(wid * 2 + 1) * 256 + l * 4 + r] = acc1[r];
    }
    __syncthreads();

    {
        const int ll = tid & 63;
        const int rr = tid >> 6;
        const int ri = ll * 4 + rr;
        const int tt = t0 + ((ll >> 4) << 2) + rr;
        #pragma unroll
        for (int xt = 0; xt < 2; ++xt) {
            float sum = K0s;
            #pragma unroll
            for (int w = 0; w < 4; ++w) sum += red[(w * 2 + xt) * 256 + ri];
            const int xx = x0 + xt * 16 + (ll & 15);
            out_u[(b * 256 + tt) * 128 + xx] = sum;
        }
    }
}

extern "C" void kernel_launch(void* const* d_in, const int* in_sizes, int n_in,
                              void* d_out, int out_size, void* d_ws, size_t ws_size,
                              hipStream_t stream) {
    float* out = (float*)d_out;
    float* ws  = (float*)d_ws;

    // bf16 side-band needs 64 floats header + 1.5M shorts = ~3.15 MB
    const size_t need = 64 * sizeof(float) + (size_t)(1048576 + 524288) * 2 + 4096;
    const bool use_bf = ws_size >= need;
    unsigned short* ztbf_g = use_bf ? (unsigned short*)(ws + 64) : nullptr;
    unsigned short* pxbf_g = use_bf ? (unsigned short*)(ws + 64) + 1048576 : nullptr;

    P prm;
    prm.x       = (const float*)d_in[0];
    prm.t       = (const float*)d_in[1];
    prm.param   = (const float*)d_in[2];
    prm.p2e_W1  = (const float*)d_in[3];
    prm.p2e_b1  = (const float*)d_in[4];
    prm.p2e_W2  = (const float*)d_in[5];
    prm.p2e_b2  = (const float*)d_in[6];
    prm.e2ex_W  = (const float*)d_in[7];
    prm.e2ex_b  = (const float*)d_in[8];
    prm.e2et_W  = (const float*)d_in[9];
    prm.e2et_b  = (const float*)d_in[10];
    prm.px_Wx   = (const float*)d_in[11];
    prm.px_bx   = (const float*)d_in[12];
    prm.px_We   = (const float*)d_in[13];
    prm.px_be   = (const float*)d_in[14];
    prm.px_Wo   = (const float*)d_in[15];
    prm.px_bo   = (const float*)d_in[16];
    prm.px_mult = (const float*)d_in[17];
    prm.zt_Wx   = (const float*)d_in[18];
    prm.zt_bx   = (const float*)d_in[19];
    prm.zt_We   = (const float*)d_in[20];
    prm.zt_be   = (const float*)d_in[21];
    prm.zt_Wo   = (const float*)d_in[22];
    prm.zt_bo   = (const float*)d_in[23];
    prm.zt_mult = (const float*)d_in[24];
    prm.h0      = (const float*)d_in[25];
    prm.blk_W1  = (const float*)d_in[26];
    prm.blk_b1  = (const float*)d_in[27];
    prm.blk_Wc  = (const float*)d_in[28];
    prm.blk_bc  = (const float*)d_in[29];
    prm.blk_W2  = (const float*)d_in[30];
    prm.blk_b2  = (const float*)d_in[31];
    prm.d_W     = (const float*)d_in[32];
    prm.d_b     = (const float*)d_in[33];
    prm.out_u   = out;                        // 131072
    prm.out_zt  = out + 131072;               // 1048576
    prm.out_px  = out + 131072 + 1048576;     // 524288
    prm.ws      = ws;
    prm.ztbf_g  = ztbf_g;
    prm.pxbf_g  = pxbf_g;

    feat_kernel<<<385, 256, 0, stream>>>(prm);
    if (use_bf)
        u_bf_kernel<<<256, 256, 0, stream>>>(ztbf_g, pxbf_g, ws, out);
    else
        u_kernel<<<256, 256, 0, stream>>>(prm.out_zt, prm.out_px, ws, out);
}